// Round 1
// baseline (76.042 us; speedup 1.0000x reference)
//
#include <hip/hip_runtime.h>

// Render_78907139162146: z-buffered triangle rasterizer, 256 tris -> 256x256 RGBA,
// bilinear sample from 3x1024x1024 uvmap.
//
// Scan semantics reduce per-pixel to: winner = last argmax of z (>= zmin, ties ->
// later index), zmin = global min vertex z. Associative over index-ordered
// chunks (later chunk wins ties via >=).
//
// R6: kernel is latency/barrier-bound, not pipe-bound (~58 live tris/block,
// <5MB traffic). (a) 512-thread blocks (8 waves): halves barrier width and
// stage-phase idle fraction vs 1024; (b) chunk merge via packed u64 LDS
// atomicMax: key = (ordered_float(z)<<32)|(tri+1) -- max z, tie -> max index
// = last, exactly the scan's ">= later wins" rule; kills the 16KB cand buffer
// + 8-iter merge; (c) uvs prefetched into LDS by the otherwise-idle stage
// waves, removing a dependent ~900cy global load from the epilogue critical
// path.
//
// Bit-exactness for survivors: no FMA contraction, exact op order,
// float64-internal linspace (np.linspace computes f64, casts f32). fmin-based
// zmin is exact in any order. Winner's w1/w2 recomputed with identical ops.

#define S 256
#define TMAX 256
#define NC 4       // triangle chunks per block
#define BT 512     // threads per block (8 waves)
#define HALF 128   // pixels per block (half row)
#define MARGIN 0.02f

__global__ __launch_bounds__(BT, 4) void render_kernel(
    const float* __restrict__ tris,
    const float* __restrict__ uvs,
    const float* __restrict__ uvmap,
    float* __restrict__ out,
    int T)
{
#pragma clang fp contract(off)
    // Per-triangle record, 4 x float4:
    //  r0: Bx, By, (Ay-By), (Ax-Bx)    -> pAB = (px-Bx)*r0.z - (py-By)*r0.w
    //  r1: Cx, Cy, (By-Cy), (Bx-Cx)    -> pCB
    //  r2: Ax, Ay, (Cy-Ay), (Cx-Ax)    -> pCA
    //  r3: ws, Az, Bz, Cz
    __shared__ float4 sd[TMAX][4];                 // 16 KB
    __shared__ float  suv[TMAX * 6];               // 6 KB (uvs, pre-transformed *2-1)
    __shared__ int    list[TMAX];                  // 1 KB
    __shared__ unsigned long long masks[4];
    __shared__ float  zpart[4];
    __shared__ unsigned long long pix[HALF];       // 1 KB packed (zkey, tri+1)

    const int tid  = threadIdx.x;
    const int bid  = blockIdx.x;
    const int row  = bid >> 1;          // output row
    const int half = bid & 1;           // which half of the row
    const int j    = half * HALF + (tid & (HALF - 1));   // output col
    const int c    = tid >> 7;          // chunk 0..3 (uniform per wave)

    // pts[row,j] = (lin[j], lin[255-row]); np.linspace computes f64, casts f32.
    const float px = (float)(-1.0 + (double)j * (2.0 / 255.0));
    const float py = (float)(-1.0 + (double)(S - 1 - row) * (2.0 / 255.0));
    // block x-window (inclusive pixel extremes of this half-row)
    const float pxlo = (float)(-1.0 + (double)(half * HALF) * (2.0 / 255.0));
    const float pxhi = (float)(-1.0 + (double)(half * HALF + HALF - 1) * (2.0 / 255.0));

    // ---- stage records + cull flag + per-wave zmin (waves 0..3);
    //      waves 4..7 prefetch uvs into LDS ----
    bool keep = false;
    float zl = 3.0e38f;
    if (tid < TMAX) {
        if (tid < T) {
            const float* p = tris + tid * 9;
            float Ax = p[0], Ay = p[1], Az = p[2];
            float Bx = p[3], By = p[4], Bz = p[5];
            float Cx = p[6], Cy = p[7], Cz = p[8];
            float w = (Bx - Ax) * (Cy - Ay) - (By - Ay) * (Cx - Ax);
            bool valid = (w >= 1e-9f);
            sd[tid][0] = make_float4(Bx, By, Ay - By, Ax - Bx);
            sd[tid][1] = make_float4(Cx, Cy, By - Cy, Bx - Cx);
            sd[tid][2] = make_float4(Ax, Ay, Cy - Ay, Cx - Ax);
            sd[tid][3] = make_float4(valid ? w : 1.0f, Az, Bz, Cz);
            zl = fminf(Az, fminf(Bz, Cz));
            float ymn = fminf(Ay, fminf(By, Cy));
            float ymx = fmaxf(Ay, fmaxf(By, Cy));
            float xmn = fminf(Ax, fminf(Bx, Cx));
            float xmx = fmaxf(Ax, fmaxf(Bx, Cx));
            // cull margin 0.02 >> ~3e-6 float edge-function rounding bound
            keep = valid && (py >= ymn - MARGIN) && (py <= ymx + MARGIN)
                         && (pxhi >= xmn - MARGIN) && (pxlo <= xmx + MARGIN);
        }
    } else {
        // waves 4..7: stage uvs (T*6 floats), coalesced, pre-transform *2-1
        for (int i = tid - TMAX; i < T * 6; i += BT - TMAX)
            suv[i] = uvs[i] * 2.0f - 1.0f;
    }
    unsigned long long m = __ballot(keep);
    if (tid < TMAX) {
        float zw = zl;
        #pragma unroll
        for (int o = 32; o > 0; o >>= 1) zw = fminf(zw, __shfl_xor(zw, o, 64));
        if ((tid & 63) == 0) { masks[tid >> 6] = m; zpart[tid >> 6] = zw; }
    }
    __syncthreads();   // barrier 1: masks, zpart, sd, suv visible

    // every thread computes prefix offsets locally (4 popcnts, no barrier)
    int n0 = __popcll(masks[0]);
    int n1 = __popcll(masks[1]);
    int n2 = __popcll(masks[2]);
    int n3 = __popcll(masks[3]);
    const int nlive = n0 + n1 + n2 + n3;
    const float zmin = fminf(fminf(zpart[0], zpart[1]), fminf(zpart[2], zpart[3]));

    // order-preserving compaction (waves 0..3); pix init (first 2 waves)
    if (tid < TMAX && keep) {
        int lane = tid & 63;
        int wv   = tid >> 6;
        int off  = (wv > 0 ? n0 : 0) + (wv > 1 ? n1 : 0) + (wv > 2 ? n2 : 0);
        int pos  = off + __popcll(masks[wv] & ((1ull << lane) - 1ull));
        list[pos] = tid;
    }
    if (tid < HALF) pix[tid] = 0ull;
    __syncthreads();   // barrier 2: list, pix visible

    // ---- per-pixel rasterization over this chunk's slice of the live list ----
    const int cs = (nlive + NC - 1) / NC;
    const int tb = c * cs;
    const int te = (tb + cs < nlive) ? (tb + cs) : nlive;

    float zcur = zmin;
    int win = -1;

    for (int it = tb; it < te; ++it) {
        int tt = list[it];                       // uniform -> broadcast ds_read
        float4 r0 = sd[tt][0];
        float4 r1 = sd[tt][1];
        float4 r2 = sd[tt][2];
        float4 r3 = sd[tt][3];
        float pAB = (px - r0.x) * r0.z - (py - r0.y) * r0.w;
        float pCB = (px - r1.x) * r1.z - (py - r1.y) * r1.w;
        float pCA = (px - r2.x) * r2.z - (py - r2.y) * r2.w;
        float prod = fmaxf(pAB, 0.0f) * fmaxf(pCB, 0.0f) * fmaxf(pCA, 0.0f);
        if (prod > 0.0f) {
            float w1 = pCB / r3.x;
            float w2 = pCA / r3.x;
            float w3 = (1.0f - w1) - w2;
            float z = (w1 * r3.y + w2 * r3.z) + w3 * r3.w;
            if (z >= zcur) { zcur = z; win = tt; }   // ascending tt: later wins ties
        }
    }
    // merge across chunks: max (ordered_z, tri+1) == last argmax of z
    if (win >= 0) {
        unsigned k = __float_as_uint(zcur);
        k = (k & 0x80000000u) ? ~k : (k | 0x80000000u);   // monotone float->uint
        unsigned long long key =
            ((unsigned long long)k << 32) | (unsigned)(win + 1);
        atomicMax(&pix[tid & (HALF - 1)], key);
    }
    __syncthreads();   // barrier 3: pix final

    // ---- epilogue: recompute winner's w1/w2 (identical ops), texture sample ----
    if (tid < HALF) {
        unsigned long long key = pix[tid];
        float r = 0.0f, g = 0.0f, b = 0.0f, a = 0.0f;
        if (key) {
            int w = (int)(key & 0xffffffffu) - 1;
            a = 1.0f;
            float4 r1 = sd[w][1];
            float4 r2 = sd[w][2];
            float4 r3 = sd[w][3];
            float pCB = (px - r1.x) * r1.z - (py - r1.y) * r1.w;
            float pCA = (px - r2.x) * r2.z - (py - r2.y) * r2.w;
            float w1 = pCB / r3.x;
            float w2 = pCA / r3.x;
            float w3 = (1.0f - w1) - w2;
            const float* q = &suv[w * 6];        // pre-transformed uvs in LDS
            float ux = (w1 * q[0] + w2 * q[2]) + w3 * q[4];
            float uy = (w1 * q[1] + w2 * q[3]) + w3 * q[5];
            float X = ((ux + 1.0f) * 0.5f) * 1023.0f;
            float Y = ((uy + 1.0f) * 0.5f) * 1023.0f;
            float x0 = floorf(X), y0 = floorf(Y);
            float wx = X - x0, wy = Y - y0;
            float w00 = (1.0f - wx) * (1.0f - wy);
            float w10 = wx * (1.0f - wy);
            float w01 = (1.0f - wx) * wy;
            float w11 = wx * wy;
            float xs1 = x0 + 1.0f, ys1 = y0 + 1.0f;
            bool xin0 = (x0  >= 0.0f) && (x0  <= 1023.0f);
            bool xin1 = (xs1 >= 0.0f) && (xs1 <= 1023.0f);
            bool yin0 = (y0  >= 0.0f) && (y0  <= 1023.0f);
            bool yin1 = (ys1 >= 0.0f) && (ys1 <= 1023.0f);
            int xi0 = (int)fminf(fmaxf(x0,  0.0f), 1023.0f);
            int xi1 = (int)fminf(fmaxf(xs1, 0.0f), 1023.0f);
            int yi0 = (int)fminf(fmaxf(y0,  0.0f), 1023.0f);
            int yi1 = (int)fminf(fmaxf(ys1, 0.0f), 1023.0f);
            float acc[3];
            #pragma unroll
            for (int ch = 0; ch < 3; ++ch) {
                const float* img = uvmap + ch * (1024 * 1024);
                float v00 = (xin0 && yin0) ? img[yi0 * 1024 + xi0] : 0.0f;
                float v10 = (xin1 && yin0) ? img[yi0 * 1024 + xi1] : 0.0f;
                float v01 = (xin0 && yin1) ? img[yi1 * 1024 + xi0] : 0.0f;
                float v11 = (xin1 && yin1) ? img[yi1 * 1024 + xi1] : 0.0f;
                acc[ch] = ((v00 * w00 + v10 * w10) + v01 * w01) + v11 * w11;
            }
            r = acc[0]; g = acc[1]; b = acc[2];
        }

        const int base = row * S + j;
        out[0 * S * S + base] = r;
        out[1 * S * S + base] = g;
        out[2 * S * S + base] = b;
        out[3 * S * S + base] = a;
    }
}

extern "C" void kernel_launch(void* const* d_in, const int* in_sizes, int n_in,
                              void* d_out, int out_size, void* d_ws, size_t ws_size,
                              hipStream_t stream) {
    const float* tris  = (const float*)d_in[0];
    const float* uvs   = (const float*)d_in[1];
    const float* uvmap = (const float*)d_in[2];
    float* out = (float*)d_out;
    int T = in_sizes[0] / 9;
    if (T > TMAX) T = TMAX;
    render_kernel<<<dim3(2 * S), dim3(BT), 0, stream>>>(tris, uvs, uvmap, out, T);
}